// Round 10
// baseline (3012.572 us; speedup 1.0000x reference)
//
#include <hip/hip_runtime.h>
#include <cstdint>
#include <cstddef>

// Problem constants
#define B_    16
#define N_    4096
#define S_    1024     // NPOINT
#define K_    32       // NSAMPLE
#define CNT_F 524288.0f   // B*S*K
#define EPS_  1e-5f

// Workspace layout (bytes). Total ~188 MB.
#define OFF_NXYZ 0u                    // [B][S][3] f32              196,608
#define OFF_IDX  196608u               // [B][S][K] i32            2,097,152
#define OFF_PTST 2293760u              // [B][N][68] f32 (xyz|pts|0) 17,825,792
#define OFF_PRE  20119552u             // [BS][32][64] f16          67,108,864
#define OFF_PRE2 87228416u             // [BS][32][64] f16          67,108,864
#define OFF_PART 154337280u            // [BS][256] f32             16,777,216
#define OFF_MM3  171114496u            // [BS][2][128] f32          16,777,216
#define OFF_ACC  187891712u            // [3][256] f32                   3,072

// fma-chain dot4 for conv inner loops (continuous path, fma-safe).
// Inline function, not a macro: avoids the R9 param/member-name collision.
__device__ __forceinline__ float dot4(float acc, float4 f, float4 wt) {
  return fmaf(f.w, wt.w, fmaf(f.z, wt.z, fmaf(f.y, wt.y, fmaf(f.x, wt.x, acc))));
}

// ---------------------------------------------------------------------------
// Transpose xyz[B,3,N] + points[B,64,N] -> ptsT[B,N,68] (col 67 = 0 pad)
// ---------------------------------------------------------------------------
__global__ __launch_bounds__(256) void transpose_kernel(
    const float* __restrict__ xyz, const float* __restrict__ pts,
    float* __restrict__ ptsT) {
  __shared__ float tile[64 * 69];
  int blk = blockIdx.x;
  int b = blk >> 6;
  int n0 = (blk & 63) << 6;
  int t = threadIdx.x;
  int wave = t >> 6, ln = t & 63;
  int n = n0 + ln;
  for (int cc = wave; cc < 68; cc += 4) {
    float v;
    if (cc < 3)       v = xyz[(size_t)(b * 3 + cc) * N_ + n];
    else if (cc < 67) v = pts[(size_t)(b * 64 + (cc - 3)) * N_ + n];
    else              v = 0.f;
    tile[ln * 69 + cc] = v;
  }
  __syncthreads();
  for (int f = t; f < 64 * 68; f += 256) {
    int r = f / 68, c = f - r * 68;
    ptsT[(size_t)(b * N_ + n0 + r) * 68 + c] = tile[r * 69 + c];
  }
}

// ---------------------------------------------------------------------------
// DPP argmax step (proven R8): rotation network within 16-lane rows, then
// cross-row broadcasts; lane 63 ends with the full-wave (max, min-index).
// ---------------------------------------------------------------------------
template <int CTRL, int RM>
__device__ __forceinline__ void dpp_argmax_step(float& bv, int& bi) {
  int ovi = __builtin_amdgcn_update_dpp(__float_as_int(bv), __float_as_int(bv),
                                        CTRL, RM, 0xf, false);
  int oi  = __builtin_amdgcn_update_dpp(bi, bi, CTRL, RM, 0xf, false);
  float ov = __int_as_float(ovi);
  if (ov > bv || (ov == bv && oi < bi)) { bv = ov; bi = oi; }
}

// ---------------------------------------------------------------------------
// FPS v4 (R9/R10): SINGLE WAVE per batch, zero barriers, zero LDS deps in
// the loop. Lane L owns points {L, L+64, ...} (strided): coalesced loads,
// conflict-free LDS mirror, ascending-j scan with strict > preserves exact
// first-index argmax (within-lane smaller j = smaller index; cross-lane ties
// -> min index via DPP network). Selection arithmetic UNCHANGED (proven
// exact R1-R8): f32, contract(off), d = (dx*dx + dy*dy) + dz*dz.
// ---------------------------------------------------------------------------
__global__ __launch_bounds__(64) void fps_kernel(
    const float* __restrict__ xyz, float* __restrict__ nxyz,
    float* __restrict__ out0) {
#pragma clang fp contract(off)
  __shared__ float sx[N_], sy[N_], sz[N_];   // read-only after init
  __shared__ float scent[S_ * 3];
  int b = blockIdx.x;
  int t = threadIdx.x;   // 0..63
  const float* xb = xyz + (size_t)b * 3 * N_;
  float xr[64], yr[64], zr[64], dist[64];
#pragma unroll
  for (int j = 0; j < 64; ++j) {
    int i = j * 64 + t;                       // coalesced: lanes contiguous
    float x = xb[i], y = xb[N_ + i], z = xb[2 * N_ + i];
    xr[j] = x; yr[j] = y; zr[j] = z;
    sx[i] = x; sy[i] = y; sz[i] = z;          // bank = t%32: conflict-free
    dist[j] = 1e10f;
  }
  __syncthreads();   // single wave: trivial

  int far = 0;
  for (int s = 0; s < S_; ++s) {
    float cx = sx[far], cy = sy[far], cz = sz[far];   // uniform broadcast read
    if (t == 0) {
      scent[s * 3]     = cx;
      scent[s * 3 + 1] = cy;
      scent[s * 3 + 2] = cz;
    }
    float bv = -1.f;
    int bi = 0;
#pragma unroll
    for (int j = 0; j < 64; ++j) {
      float dx = xr[j] - cx, dy = yr[j] - cy, dz = zr[j] - cz;
      float d = dx * dx + dy * dy + dz * dz;  // left-assoc, no fma
      float nd = fminf(dist[j], d);
      dist[j] = nd;
      if (nd > bv) { bv = nd; bi = j * 64 + t; }  // strict >: first index wins
    }
    // Wave argmax (VALU-only), winner in lane 63.
    dpp_argmax_step<0x121, 0xf>(bv, bi);  // row_ror:1
    dpp_argmax_step<0x122, 0xf>(bv, bi);  // row_ror:2
    dpp_argmax_step<0x124, 0xf>(bv, bi);  // row_ror:4
    dpp_argmax_step<0x128, 0xf>(bv, bi);  // row_ror:8
    dpp_argmax_step<0x142, 0xa>(bv, bi);  // row_bcast15 -> rows 1,3
    dpp_argmax_step<0x143, 0xc>(bv, bi);  // row_bcast31 -> rows 2,3
    far = __builtin_amdgcn_readlane(bi, 63);      // uniform (SGPR)
  }
  __syncthreads();
  // Coalesced output writes from LDS staging.
  for (int f = t; f < 3 * S_; f += 64)
    nxyz[(size_t)b * 3 * S_ + f] = scent[f];        // [B][S][3]
  for (int s = t; s < S_; s += 64) {                // [B][3][S]
    out0[(size_t)b * 3 * S_ + s]          = scent[s * 3];
    out0[(size_t)b * 3 * S_ + S_ + s]     = scent[s * 3 + 1];
    out0[(size_t)b * 3 * S_ + 2 * S_ + s] = scent[s * 3 + 2];
  }
}

// ---------------------------------------------------------------------------
// Ball query: PROVEN EXACT in R6 (XLA-CPU f32 all-fma ordering). DO NOT
// MODIFY the arithmetic. Thread per query, serial scan, early break.
// ---------------------------------------------------------------------------
__global__ __launch_bounds__(64) void bq_fma_kernel(
    const float* __restrict__ xyz, const float* __restrict__ nxyz,
    int* __restrict__ idxb) {
#pragma clang fp contract(off)
  int q = blockIdx.x * 64 + threadIdx.x;
  int b = q >> 10;
  const float* xb = xyz + (size_t)b * 3 * N_;
  float cx = nxyz[(size_t)q * 3];
  float cy = nxyz[(size_t)q * 3 + 1];
  float cz = nxyz[(size_t)q * 3 + 2];
  float A = fmaf(cz, cz, fmaf(cy, cy, cx * cx));
  int* out = idxb + (size_t)q * K_;
  int found = 0, first_i = -1;
  for (int i = 0; i < N_; ++i) {
    float x = xb[i], y = xb[N_ + i], z = xb[2 * N_ + i];
    float Bv  = fmaf(z, z, fmaf(y, y, x * x));
    float dot = fmaf(cz, z, fmaf(cy, y, cx * x));
    float d = fmaf(-2.0f, dot, A + Bv);
    if (d <= 0.04f) {
      if (first_i < 0) first_i = i;
      out[found] = i;
      ++found;
      if (found >= K_) break;
    }
  }
  for (int s = found; s < K_; ++s) out[s] = first_i;
}

// ---------------------------------------------------------------------------
// Layer 0 conv (tiled, validated): gather -> 32x67 @ 67x64 -> pre f16 +
// per-block channel sum/sumsq partials. 128 thr, 4x4 register tile.
// ---------------------------------------------------------------------------
__global__ __launch_bounds__(128) void convA_kernel(
    const float* __restrict__ ptsT, const float* __restrict__ nxyz,
    const int* __restrict__ idxb, const float* __restrict__ w0,
    const float* __restrict__ b0, _Float16* __restrict__ pre,
    float* __restrict__ part) {
  __shared__ __align__(16) float sfeat[32 * 72];
  __shared__ __align__(16) float sw[64 * 76];
  __shared__ float red0[64 * 8], red1[64 * 8];
  __shared__ __align__(16) _Float16 sstage[2048];
  __shared__ int sidx[32];
  int g = blockIdx.x;
  int t = threadIdx.x;
  int b = g >> 10;
  if (t < 32) sidx[t] = idxb[(size_t)g * K_ + t];
  for (int f = t; f < 64 * 68; f += 128) {
    int c = f / 68, ci = f - c * 68;
    sw[c * 76 + ci] = (ci < 67) ? w0[c * 67 + ci] : 0.f;
  }
  const float* nx = nxyz + (size_t)g * 3;
  float ctr0 = nx[0], ctr1 = nx[1], ctr2 = nx[2];
  __syncthreads();
  for (int f = t; f < 32 * 68; f += 128) {
    int k = f / 68, ci = f - k * 68;
    float v = ptsT[(size_t)(b * N_ + sidx[k]) * 68 + ci];  // col 67 is 0
    if (ci == 0) v -= ctr0; else if (ci == 1) v -= ctr1; else if (ci == 2) v -= ctr2;
    sfeat[k * 72 + ci] = v;
  }
  __syncthreads();
  int kq = t & 7, cq = t >> 3;
  float acc[4][4] = {};
  for (int ci = 0; ci < 68; ci += 4) {
    float4 fv[4], wv[4];
#pragma unroll
    for (int kk = 0; kk < 4; ++kk) fv[kk] = *(const float4*)&sfeat[(kq + 8 * kk) * 72 + ci];
#pragma unroll
    for (int cc = 0; cc < 4; ++cc) wv[cc] = *(const float4*)&sw[(cq + 16 * cc) * 76 + ci];
#pragma unroll
    for (int kk = 0; kk < 4; ++kk)
#pragma unroll
      for (int cc = 0; cc < 4; ++cc)
        acc[kk][cc] = dot4(acc[kk][cc], fv[kk], wv[cc]);
  }
#pragma unroll
  for (int cc = 0; cc < 4; ++cc) {
    int c = cq + 16 * cc;
    float bias = b0[c];
    float s1 = 0.f, s2 = 0.f;
#pragma unroll
    for (int kk = 0; kk < 4; ++kk) {
      float v = acc[kk][cc] + bias;
      sstage[(kq + 8 * kk) * 64 + c] = (_Float16)v;
      s1 += v; s2 += v * v;
    }
    red0[c * 8 + kq] = s1; red1[c * 8 + kq] = s2;
  }
  __syncthreads();
  if (t < 64) {
    float s1 = 0.f, s2 = 0.f;
#pragma unroll
    for (int qn = 0; qn < 8; ++qn) { s1 += red0[t * 8 + qn]; s2 += red1[t * 8 + qn]; }
    part[(size_t)g * 256 + t] = s1;
    part[(size_t)g * 256 + 64 + t] = s2;
  }
  uint4* dst = (uint4*)(pre + (size_t)g * 2048);
  const uint4* srcv = (const uint4*)sstage;
  dst[t] = srcv[t];
  dst[t + 128] = srcv[t + 128];
}

// ---------------------------------------------------------------------------
// Stats reduce (coalesced, R8-proven): thread t owns channel t; block sums 64
// consecutive rows; one atomicAdd per (block, channel). accum pre-zeroed.
// ---------------------------------------------------------------------------
__global__ __launch_bounds__(256) void red_kernel(
    const float* __restrict__ part, float* __restrict__ accum) {
  int t = threadIdx.x;
  size_t base = (size_t)blockIdx.x * 64 * 256 + t;
  float a = 0.f;
#pragma unroll 8
  for (int r = 0; r < 64; ++r) a += part[base + (size_t)r * 256];
  atomicAdd(accum + t, a);
}

// ---------------------------------------------------------------------------
// Layer 1 conv (tiled): BN0+relu on pre -> conv w1 -> pre2 + stats partials.
// ---------------------------------------------------------------------------
__global__ __launch_bounds__(128) void convB_kernel(
    const _Float16* __restrict__ pre, const float* __restrict__ accum,
    const float* __restrict__ gam, const float* __restrict__ bet,
    const float* __restrict__ w1, const float* __restrict__ b1,
    _Float16* __restrict__ pre2, float* __restrict__ part) {
  __shared__ __align__(16) float sfeat[32 * 72];
  __shared__ __align__(16) float sw[64 * 76];
  __shared__ float red0[64 * 8], red1[64 * 8];
  __shared__ __align__(16) _Float16 sstage[2048];
  __shared__ float ssc[64], ssh[64];
  int g = blockIdx.x;
  int t = threadIdx.x;
  if (t < 64) {
    float mu = accum[t] * (1.f / CNT_F);
    float var = accum[64 + t] * (1.f / CNT_F) - mu * mu;
    float sc = gam[t] / sqrtf(var + EPS_);
    ssc[t] = sc; ssh[t] = bet[t] - mu * sc;
  }
  for (int f = t; f < 64 * 64; f += 128) {
    int c = f >> 6, ci = f & 63;
    sw[c * 76 + ci] = w1[f];
  }
  __syncthreads();
  const _Float16* src = pre + (size_t)g * 2048;
  for (int f = t; f < 2048; f += 128) {
    int c = f & 63;
    float v = (float)src[f] * ssc[c] + ssh[c];
    sfeat[(f >> 6) * 72 + c] = fmaxf(v, 0.f);
  }
  __syncthreads();
  int kq = t & 7, cq = t >> 3;
  float acc[4][4] = {};
  for (int ci = 0; ci < 64; ci += 4) {
    float4 fv[4], wv[4];
#pragma unroll
    for (int kk = 0; kk < 4; ++kk) fv[kk] = *(const float4*)&sfeat[(kq + 8 * kk) * 72 + ci];
#pragma unroll
    for (int cc = 0; cc < 4; ++cc) wv[cc] = *(const float4*)&sw[(cq + 16 * cc) * 76 + ci];
#pragma unroll
    for (int kk = 0; kk < 4; ++kk)
#pragma unroll
      for (int cc = 0; cc < 4; ++cc)
        acc[kk][cc] = dot4(acc[kk][cc], fv[kk], wv[cc]);
  }
#pragma unroll
  for (int cc = 0; cc < 4; ++cc) {
    int c = cq + 16 * cc;
    float bias = b1[c];
    float s1 = 0.f, s2 = 0.f;
#pragma unroll
    for (int kk = 0; kk < 4; ++kk) {
      float v = acc[kk][cc] + bias;
      sstage[(kq + 8 * kk) * 64 + c] = (_Float16)v;
      s1 += v; s2 += v * v;
    }
    red0[c * 8 + kq] = s1; red1[c * 8 + kq] = s2;
  }
  __syncthreads();
  if (t < 64) {
    float s1 = 0.f, s2 = 0.f;
#pragma unroll
    for (int qn = 0; qn < 8; ++qn) { s1 += red0[t * 8 + qn]; s2 += red1[t * 8 + qn]; }
    part[(size_t)g * 256 + t] = s1;
    part[(size_t)g * 256 + 64 + t] = s2;
  }
  uint4* dst = (uint4*)(pre2 + (size_t)g * 2048);
  const uint4* srcv = (const uint4*)sstage;
  dst[t] = srcv[t];
  dst[t + 128] = srcv[t + 128];
}

// ---------------------------------------------------------------------------
// Layer 2 conv (tiled): BN1+relu on pre2 -> conv w2 (128 out) -> stats
// partials + per-group pre-BN max/min over k (relu∘BN monotone).
// ---------------------------------------------------------------------------
__global__ __launch_bounds__(256) void convC_kernel(
    const _Float16* __restrict__ pre2, const float* __restrict__ accum,
    const float* __restrict__ gam, const float* __restrict__ bet,
    const float* __restrict__ w2, const float* __restrict__ b2,
    float* __restrict__ mm, float* __restrict__ part) {
  __shared__ __align__(16) float sfeat[32 * 72];
  __shared__ __align__(16) float sw[128 * 76];
  __shared__ float red0[128 * 8], red1[128 * 8];
  __shared__ float rmax[128 * 8], rmin[128 * 8];
  __shared__ float ssc[64], ssh[64];
  int g = blockIdx.x;
  int t = threadIdx.x;
  if (t < 64) {
    float mu = accum[t] * (1.f / CNT_F);
    float var = accum[64 + t] * (1.f / CNT_F) - mu * mu;
    float sc = gam[t] / sqrtf(var + EPS_);
    ssc[t] = sc; ssh[t] = bet[t] - mu * sc;
  }
  for (int f = t; f < 128 * 64; f += 256) {
    int c = f >> 6, ci = f & 63;
    sw[c * 76 + ci] = w2[f];
  }
  __syncthreads();
  const _Float16* src = pre2 + (size_t)g * 2048;
  for (int f = t; f < 2048; f += 256) {
    int c = f & 63;
    float v = (float)src[f] * ssc[c] + ssh[c];
    sfeat[(f >> 6) * 72 + c] = fmaxf(v, 0.f);
  }
  __syncthreads();
  int kq = t & 7, cq = t >> 3;  // cq 0..31
  float acc[4][4] = {};
  for (int ci = 0; ci < 64; ci += 4) {
    float4 fv[4], wv[4];
#pragma unroll
    for (int kk = 0; kk < 4; ++kk) fv[kk] = *(const float4*)&sfeat[(kq + 8 * kk) * 72 + ci];
#pragma unroll
    for (int cc = 0; cc < 4; ++cc) wv[cc] = *(const float4*)&sw[(cq + 32 * cc) * 76 + ci];
#pragma unroll
    for (int kk = 0; kk < 4; ++kk)
#pragma unroll
      for (int cc = 0; cc < 4; ++cc)
        acc[kk][cc] = dot4(acc[kk][cc], fv[kk], wv[cc]);
  }
#pragma unroll
  for (int cc = 0; cc < 4; ++cc) {
    int c = cq + 32 * cc;
    float bias = b2[c];
    float s1 = 0.f, s2 = 0.f, mx = -3.4e38f, mn = 3.4e38f;
#pragma unroll
    for (int kk = 0; kk < 4; ++kk) {
      float v = acc[kk][cc] + bias;
      s1 += v; s2 += v * v;
      mx = fmaxf(mx, v); mn = fminf(mn, v);
    }
    red0[c * 8 + kq] = s1; red1[c * 8 + kq] = s2;
    rmax[c * 8 + kq] = mx; rmin[c * 8 + kq] = mn;
  }
  __syncthreads();
  if (t < 128) {
    float s1 = 0.f, s2 = 0.f, mx = -3.4e38f, mn = 3.4e38f;
#pragma unroll
    for (int qn = 0; qn < 8; ++qn) {
      s1 += red0[t * 8 + qn]; s2 += red1[t * 8 + qn];
      mx = fmaxf(mx, rmax[t * 8 + qn]); mn = fminf(mn, rmin[t * 8 + qn]);
    }
    part[(size_t)g * 256 + t] = s1;
    part[(size_t)g * 256 + 128 + t] = s2;
    mm[(size_t)g * 256 + t] = mx;
    mm[(size_t)g * 256 + 128 + t] = mn;
  }
}

// ---------------------------------------------------------------------------
// Final (coalesced, R8-proven): block = (b, 64-s tile); read mm rows, LDS
// transpose, write out[B,128,S] coalesced in s.
// ---------------------------------------------------------------------------
__global__ __launch_bounds__(256) void fin_kernel(
    const float* __restrict__ mm, const float* __restrict__ accum,
    const float* __restrict__ gam, const float* __restrict__ bet,
    float* __restrict__ out1) {
  __shared__ float tile[128 * 65];
  __shared__ float ssc[128], ssh[128];
  int blk = blockIdx.x;
  int b = blk >> 4;
  int s0 = (blk & 15) << 6;
  int t = threadIdx.x;
  if (t < 128) {
    float mu = accum[t] * (1.f / CNT_F);
    float var = accum[128 + t] * (1.f / CNT_F) - mu * mu;
    float sc = gam[t] / sqrtf(var + EPS_);
    ssc[t] = sc; ssh[t] = bet[t] - mu * sc;
  }
  __syncthreads();
  for (int f = t; f < 64 * 128; f += 256) {
    int sl = f >> 7, c = f & 127;
    const float* row = mm + (size_t)(b * S_ + s0 + sl) * 256;
    float sc = ssc[c];
    float v = (sc >= 0.f) ? row[c] : row[128 + c];
    tile[c * 65 + sl] = fmaxf(v * sc + ssh[c], 0.f);
  }
  __syncthreads();
  for (int f = t; f < 128 * 64; f += 256) {
    int c = f >> 6, sl = f & 63;
    out1[(size_t)b * 131072 + c * 1024 + s0 + sl] = tile[c * 65 + sl];
  }
}

// ---------------------------------------------------------------------------
extern "C" void kernel_launch(void* const* d_in, const int* in_sizes, int n_in,
                              void* d_out, int out_size, void* d_ws, size_t ws_size,
                              hipStream_t stream) {
  const float* xyz = (const float*)d_in[0];
  const float* pts = (const float*)d_in[1];
  const float* w0  = (const float*)d_in[2];
  const float* b0  = (const float*)d_in[3];
  const float* g0  = (const float*)d_in[4];
  const float* bt0 = (const float*)d_in[5];
  const float* w1  = (const float*)d_in[6];
  const float* b1  = (const float*)d_in[7];
  const float* g1  = (const float*)d_in[8];
  const float* bt1 = (const float*)d_in[9];
  const float* w2  = (const float*)d_in[10];
  const float* b2  = (const float*)d_in[11];
  const float* g2  = (const float*)d_in[12];
  const float* bt2 = (const float*)d_in[13];
  float* out = (float*)d_out;

  char* ws = (char*)d_ws;
  float*    nxyz  = (float*)(ws + OFF_NXYZ);
  int*      idxb  = (int*)(ws + OFF_IDX);
  float*    ptsT  = (float*)(ws + OFF_PTST);
  _Float16* pre   = (_Float16*)(ws + OFF_PRE);
  _Float16* pre2  = (_Float16*)(ws + OFF_PRE2);
  float*    part  = (float*)(ws + OFF_PART);
  float*    mm    = (float*)(ws + OFF_MM3);
  float*    accum = (float*)(ws + OFF_ACC);

  (void)hipMemsetAsync(accum, 0, 3 * 256 * sizeof(float), stream);

  fps_kernel<<<B_, 64, 0, stream>>>(xyz, nxyz, out);
  transpose_kernel<<<B_ * (N_ / 64), 256, 0, stream>>>(xyz, pts, ptsT);
  bq_fma_kernel<<<(B_ * S_) / 64, 64, 0, stream>>>(xyz, nxyz, idxb);

  convA_kernel<<<B_ * S_, 128, 0, stream>>>(ptsT, nxyz, idxb, w0, b0, pre, part);
  red_kernel<<<256, 256, 0, stream>>>(part, accum);
  convB_kernel<<<B_ * S_, 128, 0, stream>>>(pre, accum, g0, bt0, w1, b1, pre2, part);
  red_kernel<<<256, 256, 0, stream>>>(part, accum + 256);
  convC_kernel<<<B_ * S_, 256, 0, stream>>>(pre2, accum + 256, g1, bt1, w2, b2, mm, part);
  red_kernel<<<256, 256, 0, stream>>>(part, accum + 512);
  fin_kernel<<<B_ * (S_ / 64), 256, 0, stream>>>(mm, accum + 512, g2, bt2,
                                                 out + B_ * 3 * S_);
}

// Round 11
// 2270.770 us; speedup vs baseline: 1.3267x; 1.3267x over previous
//
#include <hip/hip_runtime.h>
#include <cstdint>
#include <cstddef>

// Problem constants
#define B_    16
#define N_    4096
#define S_    1024     // NPOINT
#define K_    32       // NSAMPLE
#define CNT_F 524288.0f   // B*S*K
#define EPS_  1e-5f

// Workspace layout (bytes). Total ~188 MB.
#define OFF_NXYZ 0u                    // [B][S][3] f32              196,608
#define OFF_IDX  196608u               // [B][S][K] i32            2,097,152
#define OFF_PTST 2293760u              // [B][N][68] f32 (xyz|pts|0) 17,825,792
#define OFF_PRE  20119552u             // [BS][32][64] f16          67,108,864
#define OFF_PRE2 87228416u             // [BS][32][64] f16          67,108,864
#define OFF_PART 154337280u            // [BS][256] f32             16,777,216
#define OFF_MM3  171114496u            // [BS][2][128] f32          16,777,216
#define OFF_ACC  187891712u            // [3][256] f32                   3,072

// fma-chain dot4 for conv inner loops (continuous path, fma-safe).
__device__ __forceinline__ float dot4(float acc, float4 f, float4 wt) {
  return fmaf(f.w, wt.w, fmaf(f.z, wt.z, fmaf(f.y, wt.y, fmaf(f.x, wt.x, acc))));
}

// ---------------------------------------------------------------------------
// Transpose xyz[B,3,N] + points[B,64,N] -> ptsT[B,N,68] (col 67 = 0 pad)
// ---------------------------------------------------------------------------
__global__ __launch_bounds__(256) void transpose_kernel(
    const float* __restrict__ xyz, const float* __restrict__ pts,
    float* __restrict__ ptsT) {
  __shared__ float tile[64 * 69];
  int blk = blockIdx.x;
  int b = blk >> 6;
  int n0 = (blk & 63) << 6;
  int t = threadIdx.x;
  int wave = t >> 6, ln = t & 63;
  int n = n0 + ln;
  for (int cc = wave; cc < 68; cc += 4) {
    float v;
    if (cc < 3)       v = xyz[(size_t)(b * 3 + cc) * N_ + n];
    else if (cc < 67) v = pts[(size_t)(b * 64 + (cc - 3)) * N_ + n];
    else              v = 0.f;
    tile[ln * 69 + cc] = v;
  }
  __syncthreads();
  for (int f = t; f < 64 * 68; f += 256) {
    int r = f / 68, c = f - r * 68;
    ptsT[(size_t)(b * N_ + n0 + r) * 68 + c] = tile[r * 69 + c];
  }
}

// ---------------------------------------------------------------------------
// DPP argmax step (proven R8): rotation network within 16-lane rows, then
// cross-row broadcasts; lane 63 ends with the full-wave (max, min-index).
// ---------------------------------------------------------------------------
template <int CTRL, int RM>
__device__ __forceinline__ void dpp_argmax_step(float& bv, int& bi) {
  int ovi = __builtin_amdgcn_update_dpp(__float_as_int(bv), __float_as_int(bv),
                                        CTRL, RM, 0xf, false);
  int oi  = __builtin_amdgcn_update_dpp(bi, bi, CTRL, RM, 0xf, false);
  float ov = __int_as_float(ovi);
  if (ov > bv || (ov == bv && oi < bi)) { bv = ov; bi = oi; }
}

// ---------------------------------------------------------------------------
// FPS v5 (R11): 4 waves (256 thr), 16 pts/lane in REGISTERS — ~104 VGPRs,
// under the 128 step, so NO scratch spill (v4's 64 pts/lane spilled: VGPR
// count 136 << 256 needed -> scratch traffic dominated at 4050 cyc/iter).
// 4 waves land on the CU's 4 SIMDs -> minimal barrier skew; double-buffered
// LDS reduction slots (v3-proven). Lane owns i = j*256 + t: coalesced loads,
// conflict-free LDS mirror, ascending-j scan preserves exact first-index
// argmax; cross-lane/wave ties -> min index. Selection arithmetic UNCHANGED
// (proven exact R1-R10): f32, contract(off), d = (dx*dx + dy*dy) + dz*dz.
// ---------------------------------------------------------------------------
__global__ __launch_bounds__(256) void fps_kernel(
    const float* __restrict__ xyz, float* __restrict__ nxyz,
    float* __restrict__ out0) {
#pragma clang fp contract(off)
  __shared__ float sx[N_], sy[N_], sz[N_];   // read-only after init
  __shared__ float scent[S_ * 3];
  __shared__ float redv[2][4];
  __shared__ int   redi[2][4];
  int b = blockIdx.x;
  int t = threadIdx.x;   // 0..255
  const float* xb = xyz + (size_t)b * 3 * N_;
  float xr[16], yr[16], zr[16], dist[16];
#pragma unroll
  for (int j = 0; j < 16; ++j) {
    int i = j * 256 + t;                      // coalesced: lanes contiguous
    float x = xb[i], y = xb[N_ + i], z = xb[2 * N_ + i];
    xr[j] = x; yr[j] = y; zr[j] = z;
    sx[i] = x; sy[i] = y; sz[i] = z;          // bank = t%32: conflict-free
    dist[j] = 1e10f;
  }
  __syncthreads();

  int far = 0, par = 0;
  for (int s = 0; s < S_; ++s) {
    float cx = sx[far], cy = sy[far], cz = sz[far];   // uniform broadcast read
    if (t == 0) {
      scent[s * 3]     = cx;
      scent[s * 3 + 1] = cy;
      scent[s * 3 + 2] = cz;
    }
    float bv = -1.f;
    int bi = 0;
#pragma unroll
    for (int j = 0; j < 16; ++j) {
      float dx = xr[j] - cx, dy = yr[j] - cy, dz = zr[j] - cz;
      float d = dx * dx + dy * dy + dz * dz;  // left-assoc, no fma
      float nd = fminf(dist[j], d);
      dist[j] = nd;
      if (nd > bv) { bv = nd; bi = j * 256 + t; }  // strict >: first index wins
    }
    // Wave argmax (VALU-only), winner in lane 63 of each wave.
    dpp_argmax_step<0x121, 0xf>(bv, bi);  // row_ror:1
    dpp_argmax_step<0x122, 0xf>(bv, bi);  // row_ror:2
    dpp_argmax_step<0x124, 0xf>(bv, bi);  // row_ror:4
    dpp_argmax_step<0x128, 0xf>(bv, bi);  // row_ror:8
    dpp_argmax_step<0x142, 0xa>(bv, bi);  // row_bcast15 -> rows 1,3
    dpp_argmax_step<0x143, 0xc>(bv, bi);  // row_bcast31 -> rows 2,3
    if ((t & 63) == 63) { redv[par][t >> 6] = bv; redi[par][t >> 6] = bi; }
    __syncthreads();
    bv = redv[par][0]; bi = redi[par][0];
#pragma unroll
    for (int w = 1; w < 4; ++w) {
      float ov = redv[par][w]; int oi = redi[par][w];
      if (ov > bv || (ov == bv && oi < bi)) { bv = ov; bi = oi; }
    }
    far = bi;
    par ^= 1;  // double-buffered red slots -> one barrier per iteration
  }
  __syncthreads();
  // Coalesced output writes from LDS staging.
  for (int f = t; f < 3 * S_; f += 256)
    nxyz[(size_t)b * 3 * S_ + f] = scent[f];        // [B][S][3]
  for (int s = t; s < S_; s += 256) {               // [B][3][S]
    out0[(size_t)b * 3 * S_ + s]          = scent[s * 3];
    out0[(size_t)b * 3 * S_ + S_ + s]     = scent[s * 3 + 1];
    out0[(size_t)b * 3 * S_ + 2 * S_ + s] = scent[s * 3 + 2];
  }
}

// ---------------------------------------------------------------------------
// Ball query: PROVEN EXACT in R6 (XLA-CPU f32 all-fma ordering). DO NOT
// MODIFY the arithmetic. Thread per query, serial scan, early break.
// ---------------------------------------------------------------------------
__global__ __launch_bounds__(64) void bq_fma_kernel(
    const float* __restrict__ xyz, const float* __restrict__ nxyz,
    int* __restrict__ idxb) {
#pragma clang fp contract(off)
  int q = blockIdx.x * 64 + threadIdx.x;
  int b = q >> 10;
  const float* xb = xyz + (size_t)b * 3 * N_;
  float cx = nxyz[(size_t)q * 3];
  float cy = nxyz[(size_t)q * 3 + 1];
  float cz = nxyz[(size_t)q * 3 + 2];
  float A = fmaf(cz, cz, fmaf(cy, cy, cx * cx));
  int* out = idxb + (size_t)q * K_;
  int found = 0, first_i = -1;
  for (int i = 0; i < N_; ++i) {
    float x = xb[i], y = xb[N_ + i], z = xb[2 * N_ + i];
    float Bv  = fmaf(z, z, fmaf(y, y, x * x));
    float dot = fmaf(cz, z, fmaf(cy, y, cx * x));
    float d = fmaf(-2.0f, dot, A + Bv);
    if (d <= 0.04f) {
      if (first_i < 0) first_i = i;
      out[found] = i;
      ++found;
      if (found >= K_) break;
    }
  }
  for (int s = found; s < K_; ++s) out[s] = first_i;
}

// ---------------------------------------------------------------------------
// Layer 0 conv (tiled, validated): gather -> 32x67 @ 67x64 -> pre f16 +
// per-block channel sum/sumsq partials. 128 thr, 4x4 register tile.
// ---------------------------------------------------------------------------
__global__ __launch_bounds__(128) void convA_kernel(
    const float* __restrict__ ptsT, const float* __restrict__ nxyz,
    const int* __restrict__ idxb, const float* __restrict__ w0,
    const float* __restrict__ b0, _Float16* __restrict__ pre,
    float* __restrict__ part) {
  __shared__ __align__(16) float sfeat[32 * 72];
  __shared__ __align__(16) float sw[64 * 76];
  __shared__ float red0[64 * 8], red1[64 * 8];
  __shared__ __align__(16) _Float16 sstage[2048];
  __shared__ int sidx[32];
  int g = blockIdx.x;
  int t = threadIdx.x;
  int b = g >> 10;
  if (t < 32) sidx[t] = idxb[(size_t)g * K_ + t];
  for (int f = t; f < 64 * 68; f += 128) {
    int c = f / 68, ci = f - c * 68;
    sw[c * 76 + ci] = (ci < 67) ? w0[c * 67 + ci] : 0.f;
  }
  const float* nx = nxyz + (size_t)g * 3;
  float ctr0 = nx[0], ctr1 = nx[1], ctr2 = nx[2];
  __syncthreads();
  for (int f = t; f < 32 * 68; f += 128) {
    int k = f / 68, ci = f - k * 68;
    float v = ptsT[(size_t)(b * N_ + sidx[k]) * 68 + ci];  // col 67 is 0
    if (ci == 0) v -= ctr0; else if (ci == 1) v -= ctr1; else if (ci == 2) v -= ctr2;
    sfeat[k * 72 + ci] = v;
  }
  __syncthreads();
  int kq = t & 7, cq = t >> 3;
  float acc[4][4] = {};
  for (int ci = 0; ci < 68; ci += 4) {
    float4 fv[4], wv[4];
#pragma unroll
    for (int kk = 0; kk < 4; ++kk) fv[kk] = *(const float4*)&sfeat[(kq + 8 * kk) * 72 + ci];
#pragma unroll
    for (int cc = 0; cc < 4; ++cc) wv[cc] = *(const float4*)&sw[(cq + 16 * cc) * 76 + ci];
#pragma unroll
    for (int kk = 0; kk < 4; ++kk)
#pragma unroll
      for (int cc = 0; cc < 4; ++cc)
        acc[kk][cc] = dot4(acc[kk][cc], fv[kk], wv[cc]);
  }
#pragma unroll
  for (int cc = 0; cc < 4; ++cc) {
    int c = cq + 16 * cc;
    float bias = b0[c];
    float s1 = 0.f, s2 = 0.f;
#pragma unroll
    for (int kk = 0; kk < 4; ++kk) {
      float v = acc[kk][cc] + bias;
      sstage[(kq + 8 * kk) * 64 + c] = (_Float16)v;
      s1 += v; s2 += v * v;
    }
    red0[c * 8 + kq] = s1; red1[c * 8 + kq] = s2;
  }
  __syncthreads();
  if (t < 64) {
    float s1 = 0.f, s2 = 0.f;
#pragma unroll
    for (int qn = 0; qn < 8; ++qn) { s1 += red0[t * 8 + qn]; s2 += red1[t * 8 + qn]; }
    part[(size_t)g * 256 + t] = s1;
    part[(size_t)g * 256 + 64 + t] = s2;
  }
  uint4* dst = (uint4*)(pre + (size_t)g * 2048);
  const uint4* srcv = (const uint4*)sstage;
  dst[t] = srcv[t];
  dst[t + 128] = srcv[t + 128];
}

// ---------------------------------------------------------------------------
// Stats reduce (coalesced, R8-proven): thread t owns channel t; block sums 64
// consecutive rows; one atomicAdd per (block, channel). accum pre-zeroed.
// ---------------------------------------------------------------------------
__global__ __launch_bounds__(256) void red_kernel(
    const float* __restrict__ part, float* __restrict__ accum) {
  int t = threadIdx.x;
  size_t base = (size_t)blockIdx.x * 64 * 256 + t;
  float a = 0.f;
#pragma unroll 8
  for (int r = 0; r < 64; ++r) a += part[base + (size_t)r * 256];
  atomicAdd(accum + t, a);
}

// ---------------------------------------------------------------------------
// Layer 1 conv (tiled): BN0+relu on pre -> conv w1 -> pre2 + stats partials.
// ---------------------------------------------------------------------------
__global__ __launch_bounds__(128) void convB_kernel(
    const _Float16* __restrict__ pre, const float* __restrict__ accum,
    const float* __restrict__ gam, const float* __restrict__ bet,
    const float* __restrict__ w1, const float* __restrict__ b1,
    _Float16* __restrict__ pre2, float* __restrict__ part) {
  __shared__ __align__(16) float sfeat[32 * 72];
  __shared__ __align__(16) float sw[64 * 76];
  __shared__ float red0[64 * 8], red1[64 * 8];
  __shared__ __align__(16) _Float16 sstage[2048];
  __shared__ float ssc[64], ssh[64];
  int g = blockIdx.x;
  int t = threadIdx.x;
  if (t < 64) {
    float mu = accum[t] * (1.f / CNT_F);
    float var = accum[64 + t] * (1.f / CNT_F) - mu * mu;
    float sc = gam[t] / sqrtf(var + EPS_);
    ssc[t] = sc; ssh[t] = bet[t] - mu * sc;
  }
  for (int f = t; f < 64 * 64; f += 128) {
    int c = f >> 6, ci = f & 63;
    sw[c * 76 + ci] = w1[f];
  }
  __syncthreads();
  const _Float16* src = pre + (size_t)g * 2048;
  for (int f = t; f < 2048; f += 128) {
    int c = f & 63;
    float v = (float)src[f] * ssc[c] + ssh[c];
    sfeat[(f >> 6) * 72 + c] = fmaxf(v, 0.f);
  }
  __syncthreads();
  int kq = t & 7, cq = t >> 3;
  float acc[4][4] = {};
  for (int ci = 0; ci < 64; ci += 4) {
    float4 fv[4], wv[4];
#pragma unroll
    for (int kk = 0; kk < 4; ++kk) fv[kk] = *(const float4*)&sfeat[(kq + 8 * kk) * 72 + ci];
#pragma unroll
    for (int cc = 0; cc < 4; ++cc) wv[cc] = *(const float4*)&sw[(cq + 16 * cc) * 76 + ci];
#pragma unroll
    for (int kk = 0; kk < 4; ++kk)
#pragma unroll
      for (int cc = 0; cc < 4; ++cc)
        acc[kk][cc] = dot4(acc[kk][cc], fv[kk], wv[cc]);
  }
#pragma unroll
  for (int cc = 0; cc < 4; ++cc) {
    int c = cq + 16 * cc;
    float bias = b1[c];
    float s1 = 0.f, s2 = 0.f;
#pragma unroll
    for (int kk = 0; kk < 4; ++kk) {
      float v = acc[kk][cc] + bias;
      sstage[(kq + 8 * kk) * 64 + c] = (_Float16)v;
      s1 += v; s2 += v * v;
    }
    red0[c * 8 + kq] = s1; red1[c * 8 + kq] = s2;
  }
  __syncthreads();
  if (t < 64) {
    float s1 = 0.f, s2 = 0.f;
#pragma unroll
    for (int qn = 0; qn < 8; ++qn) { s1 += red0[t * 8 + qn]; s2 += red1[t * 8 + qn]; }
    part[(size_t)g * 256 + t] = s1;
    part[(size_t)g * 256 + 64 + t] = s2;
  }
  uint4* dst = (uint4*)(pre2 + (size_t)g * 2048);
  const uint4* srcv = (const uint4*)sstage;
  dst[t] = srcv[t];
  dst[t + 128] = srcv[t + 128];
}

// ---------------------------------------------------------------------------
// Layer 2 conv (tiled): BN1+relu on pre2 -> conv w2 (128 out) -> stats
// partials + per-group pre-BN max/min over k (relu∘BN monotone).
// ---------------------------------------------------------------------------
__global__ __launch_bounds__(256) void convC_kernel(
    const _Float16* __restrict__ pre2, const float* __restrict__ accum,
    const float* __restrict__ gam, const float* __restrict__ bet,
    const float* __restrict__ w2, const float* __restrict__ b2,
    float* __restrict__ mm, float* __restrict__ part) {
  __shared__ __align__(16) float sfeat[32 * 72];
  __shared__ __align__(16) float sw[128 * 76];
  __shared__ float red0[128 * 8], red1[128 * 8];
  __shared__ float rmax[128 * 8], rmin[128 * 8];
  __shared__ float ssc[64], ssh[64];
  int g = blockIdx.x;
  int t = threadIdx.x;
  if (t < 64) {
    float mu = accum[t] * (1.f / CNT_F);
    float var = accum[64 + t] * (1.f / CNT_F) - mu * mu;
    float sc = gam[t] / sqrtf(var + EPS_);
    ssc[t] = sc; ssh[t] = bet[t] - mu * sc;
  }
  for (int f = t; f < 128 * 64; f += 256) {
    int c = f >> 6, ci = f & 63;
    sw[c * 76 + ci] = w2[f];
  }
  __syncthreads();
  const _Float16* src = pre2 + (size_t)g * 2048;
  for (int f = t; f < 2048; f += 256) {
    int c = f & 63;
    float v = (float)src[f] * ssc[c] + ssh[c];
    sfeat[(f >> 6) * 72 + c] = fmaxf(v, 0.f);
  }
  __syncthreads();
  int kq = t & 7, cq = t >> 3;  // cq 0..31
  float acc[4][4] = {};
  for (int ci = 0; ci < 64; ci += 4) {
    float4 fv[4], wv[4];
#pragma unroll
    for (int kk = 0; kk < 4; ++kk) fv[kk] = *(const float4*)&sfeat[(kq + 8 * kk) * 72 + ci];
#pragma unroll
    for (int cc = 0; cc < 4; ++cc) wv[cc] = *(const float4*)&sw[(cq + 32 * cc) * 76 + ci];
#pragma unroll
    for (int kk = 0; kk < 4; ++kk)
#pragma unroll
      for (int cc = 0; cc < 4; ++cc)
        acc[kk][cc] = dot4(acc[kk][cc], fv[kk], wv[cc]);
  }
#pragma unroll
  for (int cc = 0; cc < 4; ++cc) {
    int c = cq + 32 * cc;
    float bias = b2[c];
    float s1 = 0.f, s2 = 0.f, mx = -3.4e38f, mn = 3.4e38f;
#pragma unroll
    for (int kk = 0; kk < 4; ++kk) {
      float v = acc[kk][cc] + bias;
      s1 += v; s2 += v * v;
      mx = fmaxf(mx, v); mn = fminf(mn, v);
    }
    red0[c * 8 + kq] = s1; red1[c * 8 + kq] = s2;
    rmax[c * 8 + kq] = mx; rmin[c * 8 + kq] = mn;
  }
  __syncthreads();
  if (t < 128) {
    float s1 = 0.f, s2 = 0.f, mx = -3.4e38f, mn = 3.4e38f;
#pragma unroll
    for (int qn = 0; qn < 8; ++qn) {
      s1 += red0[t * 8 + qn]; s2 += red1[t * 8 + qn];
      mx = fmaxf(mx, rmax[t * 8 + qn]); mn = fminf(mn, rmin[t * 8 + qn]);
    }
    part[(size_t)g * 256 + t] = s1;
    part[(size_t)g * 256 + 128 + t] = s2;
    mm[(size_t)g * 256 + t] = mx;
    mm[(size_t)g * 256 + 128 + t] = mn;
  }
}

// ---------------------------------------------------------------------------
// Final (coalesced, R8-proven): block = (b, 64-s tile); read mm rows, LDS
// transpose, write out[B,128,S] coalesced in s.
// ---------------------------------------------------------------------------
__global__ __launch_bounds__(256) void fin_kernel(
    const float* __restrict__ mm, const float* __restrict__ accum,
    const float* __restrict__ gam, const float* __restrict__ bet,
    float* __restrict__ out1) {
  __shared__ float tile[128 * 65];
  __shared__ float ssc[128], ssh[128];
  int blk = blockIdx.x;
  int b = blk >> 4;
  int s0 = (blk & 15) << 6;
  int t = threadIdx.x;
  if (t < 128) {
    float mu = accum[t] * (1.f / CNT_F);
    float var = accum[128 + t] * (1.f / CNT_F) - mu * mu;
    float sc = gam[t] / sqrtf(var + EPS_);
    ssc[t] = sc; ssh[t] = bet[t] - mu * sc;
  }
  __syncthreads();
  for (int f = t; f < 64 * 128; f += 256) {
    int sl = f >> 7, c = f & 127;
    const float* row = mm + (size_t)(b * S_ + s0 + sl) * 256;
    float sc = ssc[c];
    float v = (sc >= 0.f) ? row[c] : row[128 + c];
    tile[c * 65 + sl] = fmaxf(v * sc + ssh[c], 0.f);
  }
  __syncthreads();
  for (int f = t; f < 128 * 64; f += 256) {
    int c = f >> 6, sl = f & 63;
    out1[(size_t)b * 131072 + c * 1024 + s0 + sl] = tile[c * 65 + sl];
  }
}

// ---------------------------------------------------------------------------
extern "C" void kernel_launch(void* const* d_in, const int* in_sizes, int n_in,
                              void* d_out, int out_size, void* d_ws, size_t ws_size,
                              hipStream_t stream) {
  const float* xyz = (const float*)d_in[0];
  const float* pts = (const float*)d_in[1];
  const float* w0  = (const float*)d_in[2];
  const float* b0  = (const float*)d_in[3];
  const float* g0  = (const float*)d_in[4];
  const float* bt0 = (const float*)d_in[5];
  const float* w1  = (const float*)d_in[6];
  const float* b1  = (const float*)d_in[7];
  const float* g1  = (const float*)d_in[8];
  const float* bt1 = (const float*)d_in[9];
  const float* w2  = (const float*)d_in[10];
  const float* b2  = (const float*)d_in[11];
  const float* g2  = (const float*)d_in[12];
  const float* bt2 = (const float*)d_in[13];
  float* out = (float*)d_out;

  char* ws = (char*)d_ws;
  float*    nxyz  = (float*)(ws + OFF_NXYZ);
  int*      idxb  = (int*)(ws + OFF_IDX);
  float*    ptsT  = (float*)(ws + OFF_PTST);
  _Float16* pre   = (_Float16*)(ws + OFF_PRE);
  _Float16* pre2  = (_Float16*)(ws + OFF_PRE2);
  float*    part  = (float*)(ws + OFF_PART);
  float*    mm    = (float*)(ws + OFF_MM3);
  float*    accum = (float*)(ws + OFF_ACC);

  (void)hipMemsetAsync(accum, 0, 3 * 256 * sizeof(float), stream);

  fps_kernel<<<B_, 256, 0, stream>>>(xyz, nxyz, out);
  transpose_kernel<<<B_ * (N_ / 64), 256, 0, stream>>>(xyz, pts, ptsT);
  bq_fma_kernel<<<(B_ * S_) / 64, 64, 0, stream>>>(xyz, nxyz, idxb);

  convA_kernel<<<B_ * S_, 128, 0, stream>>>(ptsT, nxyz, idxb, w0, b0, pre, part);
  red_kernel<<<256, 256, 0, stream>>>(part, accum);
  convB_kernel<<<B_ * S_, 128, 0, stream>>>(pre, accum, g0, bt0, w1, b1, pre2, part);
  red_kernel<<<256, 256, 0, stream>>>(part, accum + 256);
  convC_kernel<<<B_ * S_, 256, 0, stream>>>(pre2, accum + 256, g1, bt1, w2, b2, mm, part);
  red_kernel<<<256, 256, 0, stream>>>(part, accum + 512);
  fin_kernel<<<B_ * (S_ / 64), 256, 0, stream>>>(mm, accum + 512, g2, bt2,
                                                 out + B_ * 3 * S_);
}